// Round 9
// baseline (1046.331 us; speedup 1.0000x reference)
//
#include <hip/hip_runtime.h>
#include <math.h>

#define NOUTK 1024
#define PHK   512
#define HID   24
#define G4    96
#define LSTEPS 32
#define BATCH 8192
#define EPB   16        // fallback kernel's elements/block
#define EPBS  8         // main kernel: 8 elements / 512-thread block

// ---------------- main path: EPBS=8, 512-thread blocks, ~33 KB LDS ---------
// All per-step weight operands PRE-WIDENED to f64 (exact) so the inner loops
// have zero v_cvt_f64_f32: whhT/blin/bihs/bhhs f64 in LDS, wlinKC f64 in ws.
struct SmemS {
  double whhT[HID][G4];       // w_hh transposed f64 [k][row]           18432 B
  double blin[NOUTK];         // b_lin f64                               8192 B
  double bihs[G4], bhhs[G4];  //                                         1536 B
  double hsh[EPBS][25];       // h state f64 (pad 25)                    1600 B
  double scrM[8][EPBS];       // max partials                             512 B
  double scrS[8][EPBS];       // sum partials                             512 B
  double candr[8][EPBS];      // crossing candidate probs                 512 B
  double tots[8][EPBS];       // per-slice prob totals                    512 B
  double r0sh[EPBS];          //                                           64 B
  float  ubuf[LSTEPS][EPBS];  // all 32 steps of u                       1024 B
  int    candj[8][EPBS];      //                                          256 B
  int    actsh[EPBS];         // previous action (-1 = zeros one-hot)      32 B
};

// ---------------- fallback (ws too small): R5's proven dynamic-LDS kernel --
struct SmemD {
  float  stg[HID][128][8];
  float  whhT[HID][G4];
  float  blin[NOUTK];
  float  bihs[G4], bhhs[G4];
  double hsh[EPB][25];
  double scrM[8][EPB];
  double scrS[8][EPB];
  double candr[8][EPB];
  double tots[8][EPB];
  double r0sh[EPB];
  float  ubuf[LSTEPS][EPB];
  int    candj[8][EPB];
  int    actsh[EPB];
};

__device__ __forceinline__ float bf2f(unsigned short v) {
  union { unsigned u; float f; } x; x.u = ((unsigned)v) << 16; return x.f;
}
__device__ __forceinline__ unsigned short f2bf(float f) {
  unsigned u = __float_as_uint(f);
  unsigned r = 0x7FFFu + ((u >> 16) & 1u);
  return (unsigned short)((u + r) >> 16);
}
__device__ __forceinline__ float bfsnap(float f) { return bf2f(f2bf(f)); }

// Workspace prep, tier A (f64 weights):
//   wsf[0 .. 98303]  = wihT [1024][96] f32   (393,216 B)
//   wsd[0 .. 24575]  = wlinKC[24][1024] f64  (196,608 B, 8B-aligned offset)
__global__ void __launch_bounds__(256)
prep_ws64(const float* __restrict__ wihf, const float* __restrict__ wlinf,
          float* __restrict__ wsf, double* __restrict__ wsd) {
  const int idx = blockIdx.x * 256 + threadIdx.x;   // 0..122879
  if (idx < NOUTK * G4) {
    const int j = idx / G4;                    // column of w_ih  0..1023
    const int r = idx - j * G4;                // row of w_ih     0..95
    wsf[idx] = wihf[r * NOUTK + j];
  } else {
    const int i2  = idx - NOUTK * G4;          // 0..24575
    const int k   = i2 >> 10;                  // 0..23
    const int col = i2 & (NOUTK - 1);          // 0..1023
    wsd[i2] = (double)wlinf[col * HID + k];    // exact widening
  }
}

// tier B prep (f32 wlinKC, R8 behavior) for smaller workspaces
__global__ void __launch_bounds__(256)
prep_ws32(const float* __restrict__ wihf, const float* __restrict__ wlinf,
          float* __restrict__ ws, int total) {
  const int idx = blockIdx.x * 256 + threadIdx.x;
  if (idx >= total) return;
  if (idx < NOUTK * G4) {
    const int j = idx / G4;
    const int r = idx - j * G4;
    ws[idx] = wihf[r * NOUTK + j];
  } else {
    const int i2  = idx - NOUTK * G4;
    const int k   = i2 >> 10;
    const int col = i2 & (NOUTK - 1);
    ws[idx] = wlinf[col * HID + k];
  }
}

// R8 post-mortem: 824us, VALUBusy 69% at the 32-wave HW cap -> VALU-issue-
// bound. Issue audit: the f32->f64 convert stream (192 cvts/thread/step in
// phase G + ~100 in phase L) rivals the fma stream itself. R9 removes it by
// pre-widening all weight operands to f64 (exact; same fma order -> decisions
// bit-identical to R8). Phase G f64 loop at unroll 1 keeps the load window
// (4x16B = 8 regs) inside the 32-VGPR budget. Structure/barriers/race-fix
// unchanged from R8.
__global__ void __launch_bounds__(512, 8)
policy_g(const float* __restrict__ whhf,  const float* __restrict__ bihf,
         const float* __restrict__ bhhf,  const float* __restrict__ blinf,
         const float* __restrict__ uf,    const float* __restrict__ wT,
         const float* __restrict__ wKC32, const double* __restrict__ wKC64,
         float* __restrict__ outg) {
  __shared__ SmemS smS;
  SmemS* sm = &smS;
  const int tid  = threadIdx.x;
  const int wave = tid >> 6;                 // 8 waves
  const int lane = tid & 63;
  const int s    = wave;                     // slice: 64 active cols
  const int le   = lane & 7;                 // element within block (0..7)
  const int jl   = lane >> 3;                // 8-col chunk within slice
  const int eG   = le;                       // element this thread computes for
  const int geL  = blockIdx.x * EPBS + wave; // owner's global batch element
  const int jgl0 = s * 64 + jl * 8;          // active-local col of r=0

  // ---------------- one-time staging (widen to f64 once, not per step) ---
  for (int i = tid; i < G4 * HID; i += 512) {
    const int row = i / HID, k = i % HID;    // coalesced global read
    sm->whhT[k][row] = (double)whhf[i];
  }
  for (int i = tid; i < NOUTK; i += 512) sm->blin[i] = (double)blinf[i];
  if (tid < G4) {
    sm->bihs[tid] = (double)bihf[tid];
    sm->bhhs[tid] = (double)bhhf[tid];
  }
  if (tid < EPBS * 25) ((double*)sm->hsh)[tid] = 0.0;
  if (tid < EPBS) sm->actsh[tid] = -1;
  if (tid < LSTEPS * EPBS) {                 // preload ALL u for this block
    const int t = tid >> 3, e = tid & 7;
    sm->ubuf[t][e] = uf[t * BATCH + blockIdx.x * EPBS + e];
  }

  double creg = 0.0;          // c state: waves 0-3, lanes {0-23, 32-55}
  __syncthreads();

  for (int t = 0; t < LSTEPS; ++t) {
    const int odd  = t & 1;
    const int base = odd ? PHK : 0;

    // ---------------- phase L: LSTM cell, 2 elements per wave ------------
    // whhT/bihs/bhhs now f64 in LDS: zero cvts in the gate loops. Same
    // per-gate fma order (k ascending) -> gates bit-identical.
    if (wave < 4 && (lane & 31) < HID) {
      const int eL = (wave << 1) + (lane >> 5);   // element 0..7
      const int rl = lane & 31;                   // row within gate (0..23)
      const int a  = sm->actsh[eL];
      double g0, g1, g2, g3;
#define GATE(Q, GOUT)                                                        \
      { const int row = (Q) * HID + rl;                                      \
        const double colA = (a >= 0) ? (double)wT[a * G4 + row] : 0.0;       \
        double mv = 0.0;                                                     \
        _Pragma("unroll 4")                                                  \
        for (int k = 0; k < HID; ++k)                                        \
          mv = fma(sm->hsh[eL][k], sm->whhT[k][row], mv);                    \
        GOUT = ((colA + sm->bihs[row]) + mv) + sm->bhhs[row];                \
        __builtin_amdgcn_sched_barrier(0); }
      GATE(0, g0) GATE(1, g1) GATE(2, g2) GATE(3, g3)
#undef GATE
      const double ig = 1.0 / (1.0 + exp(-g0));
      const double fg = 1.0 / (1.0 + exp(-g1));
      const double gv = tanh(g2);
      const double og = 1.0 / (1.0 + exp(-g3));
      creg = fg * creg + ig * gv;
      sm->hsh[eL][rl] = og * tanh(creg);
    }
    __syncthreads();                                  // b1

    // ---------------- phase G: logits, f64 weights (zero cvt) ------------
    double z0 = 0.0, z1 = 0.0, z2 = 0.0, z3 = 0.0,
           z4 = 0.0, z5 = 0.0, z6 = 0.0, z7 = 0.0;
    if (wKC64) {
      const double* __restrict__ wrow = wKC64 + (base + jgl0);
      #pragma unroll 1
      for (int k = 0; k < HID; ++k) {             // unroll 1: 4x16B window
        const double  hv  = sm->hsh[eG][k];       // fits the 32-VGPR budget
        const double2 wa0 = *(const double2*)(wrow + k * NOUTK);
        const double2 wa1 = *(const double2*)(wrow + k * NOUTK + 2);
        const double2 wb0 = *(const double2*)(wrow + k * NOUTK + 4);
        const double2 wb1 = *(const double2*)(wrow + k * NOUTK + 6);
        z0 = fma(hv, wa0.x, z0); z1 = fma(hv, wa0.y, z1);
        z2 = fma(hv, wa1.x, z2); z3 = fma(hv, wa1.y, z3);
        z4 = fma(hv, wb0.x, z4); z5 = fma(hv, wb0.y, z5);
        z6 = fma(hv, wb1.x, z6); z7 = fma(hv, wb1.y, z7);
      }
    } else {                                      // tier B: R8's f32 path
      const float* __restrict__ wrow = wKC32 + (base + jgl0);
      #pragma unroll 2
      for (int k = 0; k < HID; ++k) {
        const double hv = sm->hsh[eG][k];
        const float4 wa = *(const float4*)(wrow + k * NOUTK);
        const float4 wb = *(const float4*)(wrow + k * NOUTK + 4);
        z0 = fma(hv, (double)wa.x, z0); z1 = fma(hv, (double)wa.y, z1);
        z2 = fma(hv, (double)wa.z, z2); z3 = fma(hv, (double)wa.w, z3);
        z4 = fma(hv, (double)wb.x, z4); z5 = fma(hv, (double)wb.y, z5);
        z6 = fma(hv, (double)wb.z, z6); z7 = fma(hv, (double)wb.w, z7);
      }
    }
    {
      const double2 ba0 = *(const double2*)&sm->blin[base + jgl0];
      const double2 ba1 = *(const double2*)&sm->blin[base + jgl0 + 2];
      const double2 bb0 = *(const double2*)&sm->blin[base + jgl0 + 4];
      const double2 bb1 = *(const double2*)&sm->blin[base + jgl0 + 6];
      z0 += ba0.x; z1 += ba0.y; z2 += ba1.x; z3 += ba1.y;
      z4 += bb0.x; z5 += bb0.y; z6 += bb1.x; z7 += bb1.y;
    }

    // ---------------- softmax max: partials -> ONE barrier -> self-serve -
    double pm = fmax(fmax(fmax(z0, z1), fmax(z2, z3)),
                     fmax(fmax(z4, z5), fmax(z6, z7)));
    pm = fmax(pm, __shfl_xor(pm, 8));
    pm = fmax(pm, __shfl_xor(pm, 16));
    pm = fmax(pm, __shfl_xor(pm, 32));
    if (jl == 0) sm->scrM[s][eG] = pm;
    __syncthreads();                                  // B2
    double Me;
    {
      const double s0 = sm->scrM[0][eG], s1 = sm->scrM[1][eG],
                   s2 = sm->scrM[2][eG], s3 = sm->scrM[3][eG],
                   s4 = sm->scrM[4][eG], s5 = sm->scrM[5][eG],
                   s6 = sm->scrM[6][eG], s7 = sm->scrM[7][eG];
      Me = fmax(fmax(fmax(s0, s1), fmax(s2, s3)),
                fmax(fmax(s4, s5), fmax(s6, s7)));
    }

    // ---------------- exp (fenced pairs) + masked-sum partials ----
    z0 = exp(z0 - Me); z1 = exp(z1 - Me);
    __builtin_amdgcn_sched_barrier(0);
    z2 = exp(z2 - Me); z3 = exp(z3 - Me);
    __builtin_amdgcn_sched_barrier(0);
    z4 = exp(z4 - Me); z5 = exp(z5 - Me);
    __builtin_amdgcn_sched_barrier(0);
    z6 = exp(z6 - Me); z7 = exp(z7 - Me);
    double ps = ((((((z0 + z1) + z2) + z3) + z4) + z5) + z6) + z7;
    ps += __shfl_xor(ps, 8);
    ps += __shfl_xor(ps, 16);
    ps += __shfl_xor(ps, 32);
    if (jl == 0) sm->scrS[s][eG] = ps;
    __syncthreads();                                  // B4
    double inv;
    {
      const double s0 = sm->scrS[0][eG], s1 = sm->scrS[1][eG],
                   s2 = sm->scrS[2][eG], s3 = sm->scrS[3][eG],
                   s4 = sm->scrS[4][eG], s5 = sm->scrS[5][eG],
                   s6 = sm->scrS[6][eG], s7 = sm->scrS[7][eG];
      inv = 1.0 / (((s0 + s1) + (s2 + s3)) + ((s4 + s5) + (s6 + s7)));
    }

    // ---------------- rr = e/Sm, blocked prefix (z's die here) ----
    const double p0 = z0 * inv,      p1 = p0 + z1 * inv,
                 p2 = p1 + z2 * inv, p3 = p2 + z3 * inv;
    const double p4 = p3 + z4 * inv, p5 = p4 + z5 * inv,
                 p6 = p5 + z6 * inv, p7 = p6 + z7 * inv;
    double exbase = 0.0, acc = 0.0;
    #pragma unroll
    for (int q2 = 0; q2 < 8; ++q2) {
      const double tq = __shfl(p7, q2 * 8 + le);
      if (q2 == jl) exbase = acc;
      acc += tq;
    }
    if (jl == 0) sm->tots[s][eG] = acc;
    if (s == 0 && lane < 8) sm->r0sh[eG] = p0;        // p0 == z0*inv exactly
    __syncthreads();                                  // b6

    // ---------------- crossing search ----
    double sb = exbase;
    for (int i = 0; i < s; ++i) sb += sm->tots[i][eG];
    const double ue = (double)sm->ubuf[t][eG];
    int jloc = 0x7FFFFFFF; double rsel = 0.0;
#define CROSS(R, PR, PRM1)                                                   \
    { const double C = sb + PR;                                              \
      if (jloc == 0x7FFFFFFF && C > ue) {                                    \
        jloc = jgl0 + (R); rsel = ((R) == 0) ? (PR) : ((PR) - (PRM1)); } }
    CROSS(0, p0, p0) CROSS(1, p1, p0) CROSS(2, p2, p1) CROSS(3, p3, p2)
    CROSS(4, p4, p3) CROSS(5, p5, p4) CROSS(6, p6, p5) CROSS(7, p7, p6)
#undef CROSS
    { int oj = __shfl_xor(jloc, 8);  double orr = __shfl_xor(rsel, 8);  if (oj < jloc) { jloc = oj; rsel = orr; } }
    { int oj = __shfl_xor(jloc, 16); double orr = __shfl_xor(rsel, 16); if (oj < jloc) { jloc = oj; rsel = orr; } }
    { int oj = __shfl_xor(jloc, 32); double orr = __shfl_xor(rsel, 32); if (oj < jloc) { jloc = oj; rsel = orr; } }
    if (jl == 0) { sm->candj[s][eG] = jloc; sm->candr[s][eG] = rsel; }
    __syncthreads();                                  // b7

    // ---------------- owner: combine slices, emit (wave w = element w) ---
    if (lane < 8) {
      int cj = sm->candj[lane][wave]; double cr = sm->candr[lane][wave];
      { int oj = __shfl_xor(cj, 1); double orr = __shfl_xor(cr, 1); if (oj < cj) { cj = oj; cr = orr; } }
      { int oj = __shfl_xor(cj, 2); double orr = __shfl_xor(cr, 2); if (oj < cj) { cj = oj; cr = orr; } }
      { int oj = __shfl_xor(cj, 4); double orr = __shfl_xor(cr, 4); if (oj < cj) { cj = oj; cr = orr; } }
      if (lane == 0) {
        int actg; double p;
        if (cj == 0x7FFFFFFF) {               // cumsum never exceeded u:
          actg = 0;                           // np.argmax(all False) == 0
          p = odd ? 0.0 : sm->r0sh[wave];     // out[0] (masked -> 0 on odd)
        } else {
          actg = base + cj; p = cr;
        }
        sm->actsh[wave] = actg;
        const int io = geL * LSTEPS + t;
        outg[io]                  = bfsnap((float)p);
        outg[BATCH * LSTEPS + io] = bfsnap((float)actg);
      }
    }
    __syncthreads();                                  // b8: fence actsh for
                                                      // phase-L of t+1
  }
}

// ---------------- fallback: R5's proven dynamic-LDS kernel (unchanged) -----
__global__ void __launch_bounds__(1024)
policy_l(const float* __restrict__ wihf,  const float* __restrict__ whhf,
         const float* __restrict__ bihf,  const float* __restrict__ bhhf,
         const float* __restrict__ wlinf, const float* __restrict__ blinf,
         const float* __restrict__ uf,    const float* __restrict__ wT,
         float* __restrict__ outg) {
  extern __shared__ char smraw[];
  SmemD* sm = (SmemD*)smraw;
  const int tid  = threadIdx.x;
  const int wave = tid >> 6;
  const int lane = tid & 63;
  const int s    = wave & 7;
  const int eg   = (wave >> 3) << 3;
  const int le   = lane & 7;
  const int jl   = lane >> 3;
  const int eG   = eg + le;
  const int geL  = blockIdx.x * EPB + wave;
  const int jgl0 = s * 64 + jl * 8;

  {
    const float4* row4 = (const float4*)(wlinf + tid * HID);
    #pragma unroll
    for (int q = 0; q < 6; ++q) {
      const float4 v = row4[q];
      sm->stg[q * 4 + 0][tid >> 3][tid & 7] = v.x;
      sm->stg[q * 4 + 1][tid >> 3][tid & 7] = v.y;
      sm->stg[q * 4 + 2][tid >> 3][tid & 7] = v.z;
      sm->stg[q * 4 + 3][tid >> 3][tid & 7] = v.w;
    }
  }
  for (int i = tid; i < G4 * HID; i += 1024) {
    const int row = i / HID, k = i % HID;
    sm->whhT[k][row] = whhf[i];
  }
  sm->blin[tid] = blinf[tid];
  if (tid < G4) { sm->bihs[tid] = bihf[tid]; sm->bhhs[tid] = bhhf[tid]; }
  if (tid < EPB * 25) ((double*)sm->hsh)[tid] = 0.0;
  if (tid < EPB) sm->actsh[tid] = -1;
  if (tid < LSTEPS * EPB) {
    const int t = tid >> 4, e = tid & 15;
    sm->ubuf[t][e] = uf[t * BATCH + blockIdx.x * EPB + e];
  }

  double creg = 0.0;
  __syncthreads();

  for (int t = 0; t < LSTEPS; ++t) {
    const int odd  = t & 1;
    const int base = odd ? PHK : 0;
    const int c    = (base >> 3) + s * 8 + jl;

    if (wave < 8 && (lane & 31) < HID) {
      const int eL = (wave << 1) + (lane >> 5);
      const int rl = lane & 31;
      const int a  = sm->actsh[eL];
      double g0, g1, g2, g3;
#define GATE(Q, GOUT)                                                        \
      { const int row = (Q) * HID + rl;                                      \
        const double colA = (a >= 0)                                         \
            ? (double)(wT ? wT[a * G4 + row] : wihf[row * NOUTK + a])        \
            : 0.0;                                                           \
        double mv = 0.0;                                                     \
        _Pragma("unroll 4")                                                  \
        for (int k = 0; k < HID; ++k)                                        \
          mv = fma(sm->hsh[eL][k], (double)sm->whhT[k][row], mv);            \
        GOUT = ((colA + (double)sm->bihs[row]) + mv) + (double)sm->bhhs[row]; \
        __builtin_amdgcn_sched_barrier(0); }
      GATE(0, g0) GATE(1, g1) GATE(2, g2) GATE(3, g3)
#undef GATE
      const double ig = 1.0 / (1.0 + exp(-g0));
      const double fg = 1.0 / (1.0 + exp(-g1));
      const double gv = tanh(g2);
      const double og = 1.0 / (1.0 + exp(-g3));
      creg = fg * creg + ig * gv;
      sm->hsh[eL][rl] = og * tanh(creg);
    }
    __syncthreads();

    double z0 = 0.0, z1 = 0.0, z2 = 0.0, z3 = 0.0,
           z4 = 0.0, z5 = 0.0, z6 = 0.0, z7 = 0.0;
    #pragma unroll 2
    for (int k = 0; k < HID; ++k) {
      const double hv = sm->hsh[eG][k];
      const float4 wa = *(const float4*)&sm->stg[k][c][0];
      const float4 wb = *(const float4*)&sm->stg[k][c][4];
      z0 = fma(hv, (double)wa.x, z0); z1 = fma(hv, (double)wa.y, z1);
      z2 = fma(hv, (double)wa.z, z2); z3 = fma(hv, (double)wa.w, z3);
      z4 = fma(hv, (double)wb.x, z4); z5 = fma(hv, (double)wb.y, z5);
      z6 = fma(hv, (double)wb.z, z6); z7 = fma(hv, (double)wb.w, z7);
    }
    {
      const float4 ba = *(const float4*)&sm->blin[base + jgl0];
      const float4 bb = *(const float4*)&sm->blin[base + jgl0 + 4];
      z0 += (double)ba.x; z1 += (double)ba.y; z2 += (double)ba.z; z3 += (double)ba.w;
      z4 += (double)bb.x; z5 += (double)bb.y; z6 += (double)bb.z; z7 += (double)bb.w;
    }

    double pm = fmax(fmax(fmax(z0, z1), fmax(z2, z3)),
                     fmax(fmax(z4, z5), fmax(z6, z7)));
    pm = fmax(pm, __shfl_xor(pm, 8));
    pm = fmax(pm, __shfl_xor(pm, 16));
    pm = fmax(pm, __shfl_xor(pm, 32));
    if (jl == 0) sm->scrM[s][eG] = pm;
    __syncthreads();
    double Me;
    {
      const double s0 = sm->scrM[0][eG], s1 = sm->scrM[1][eG],
                   s2 = sm->scrM[2][eG], s3 = sm->scrM[3][eG],
                   s4 = sm->scrM[4][eG], s5 = sm->scrM[5][eG],
                   s6 = sm->scrM[6][eG], s7 = sm->scrM[7][eG];
      Me = fmax(fmax(fmax(s0, s1), fmax(s2, s3)),
                fmax(fmax(s4, s5), fmax(s6, s7)));
    }

    z0 = exp(z0 - Me); z1 = exp(z1 - Me);
    __builtin_amdgcn_sched_barrier(0);
    z2 = exp(z2 - Me); z3 = exp(z3 - Me);
    __builtin_amdgcn_sched_barrier(0);
    z4 = exp(z4 - Me); z5 = exp(z5 - Me);
    __builtin_amdgcn_sched_barrier(0);
    z6 = exp(z6 - Me); z7 = exp(z7 - Me);
    double ps = ((((((z0 + z1) + z2) + z3) + z4) + z5) + z6) + z7;
    ps += __shfl_xor(ps, 8);
    ps += __shfl_xor(ps, 16);
    ps += __shfl_xor(ps, 32);
    if (jl == 0) sm->scrS[s][eG] = ps;
    __syncthreads();
    double inv;
    {
      const double s0 = sm->scrS[0][eG], s1 = sm->scrS[1][eG],
                   s2 = sm->scrS[2][eG], s3 = sm->scrS[3][eG],
                   s4 = sm->scrS[4][eG], s5 = sm->scrS[5][eG],
                   s6 = sm->scrS[6][eG], s7 = sm->scrS[7][eG];
      inv = 1.0 / (((s0 + s1) + (s2 + s3)) + ((s4 + s5) + (s6 + s7)));
    }

    const double p0 = z0 * inv,      p1 = p0 + z1 * inv,
                 p2 = p1 + z2 * inv, p3 = p2 + z3 * inv;
    const double p4 = p3 + z4 * inv, p5 = p4 + z5 * inv,
                 p6 = p5 + z6 * inv, p7 = p6 + z7 * inv;
    double exbase = 0.0, acc = 0.0;
    #pragma unroll
    for (int q2 = 0; q2 < 8; ++q2) {
      const double tq = __shfl(p7, q2 * 8 + le);
      if (q2 == jl) exbase = acc;
      acc += tq;
    }
    if (jl == 0) sm->tots[s][eG] = acc;
    if (s == 0 && lane < 8) sm->r0sh[eG] = p0;
    __syncthreads();

    double sb = exbase;
    for (int i = 0; i < s; ++i) sb += sm->tots[i][eG];
    const double ue = (double)sm->ubuf[t][eG];
    int jloc = 0x7FFFFFFF; double rsel = 0.0;
#define CROSS(R, PR, PRM1)                                                   \
    { const double C = sb + PR;                                              \
      if (jloc == 0x7FFFFFFF && C > ue) {                                    \
        jloc = jgl0 + (R); rsel = ((R) == 0) ? (PR) : ((PR) - (PRM1)); } }
    CROSS(0, p0, p0) CROSS(1, p1, p0) CROSS(2, p2, p1) CROSS(3, p3, p2)
    CROSS(4, p4, p3) CROSS(5, p5, p4) CROSS(6, p6, p5) CROSS(7, p7, p6)
#undef CROSS
    { int oj = __shfl_xor(jloc, 8);  double orr = __shfl_xor(rsel, 8);  if (oj < jloc) { jloc = oj; rsel = orr; } }
    { int oj = __shfl_xor(jloc, 16); double orr = __shfl_xor(rsel, 16); if (oj < jloc) { jloc = oj; rsel = orr; } }
    { int oj = __shfl_xor(jloc, 32); double orr = __shfl_xor(rsel, 32); if (oj < jloc) { jloc = oj; rsel = orr; } }
    if (jl == 0) { sm->candj[s][eG] = jloc; sm->candr[s][eG] = rsel; }
    __syncthreads();

    if (lane < 8) {
      int cj = sm->candj[lane][wave]; double cr = sm->candr[lane][wave];
      { int oj = __shfl_xor(cj, 1); double orr = __shfl_xor(cr, 1); if (oj < cj) { cj = oj; cr = orr; } }
      { int oj = __shfl_xor(cj, 2); double orr = __shfl_xor(cr, 2); if (oj < cj) { cj = oj; cr = orr; } }
      { int oj = __shfl_xor(cj, 4); double orr = __shfl_xor(cr, 4); if (oj < cj) { cj = oj; cr = orr; } }
      if (lane == 0) {
        int actg; double p;
        if (cj == 0x7FFFFFFF) {
          actg = 0;
          p = odd ? 0.0 : sm->r0sh[wave];
        } else {
          actg = base + cj; p = cr;
        }
        sm->actsh[wave] = actg;
        const int io = geL * LSTEPS + t;
        outg[io]                  = bfsnap((float)p);
        outg[BATCH * LSTEPS + io] = bfsnap((float)actg);
      }
    }
    __syncthreads();   // fence actsh for phase-L of t+1 (race fix)
  }
}

extern "C" void kernel_launch(void* const* d_in, const int* in_sizes, int n_in,
                              void* d_out, int out_size, void* d_ws, size_t ws_size,
                              hipStream_t stream) {
  (void)in_sizes; (void)n_in; (void)out_size;
  constexpr int    WIHT_N   = NOUTK * G4;                    // 98304 f32
  constexpr int    WKC_N    = HID * NOUTK;                   // 24576 elems
  constexpr size_t WIHT_B   = (size_t)WIHT_N * sizeof(float);   // 393216 B
  const size_t need_A  = WIHT_B + (size_t)WKC_N * sizeof(double); // 589824 B
  const size_t need_B  = WIHT_B + (size_t)WKC_N * sizeof(float);  // 491520 B
  const size_t need_wt = WIHT_B;

  if (ws_size >= need_A) {                     // tier A: f64 wlinKC
    prep_ws64<<<(WIHT_N + WKC_N + 255) / 256, 256, 0, stream>>>(
        (const float*)d_in[0], (const float*)d_in[4],
        (float*)d_ws, (double*)((char*)d_ws + WIHT_B));
    policy_g<<<BATCH / EPBS, 512, 0, stream>>>(
        (const float*)d_in[1], (const float*)d_in[2], (const float*)d_in[3],
        (const float*)d_in[5], (const float*)d_in[6],
        (const float*)d_ws, nullptr,
        (const double*)((char*)d_ws + WIHT_B), (float*)d_out);
  } else if (ws_size >= need_B) {              // tier B: f32 wlinKC (R8)
    prep_ws32<<<(WIHT_N + WKC_N + 255) / 256, 256, 0, stream>>>(
        (const float*)d_in[0], (const float*)d_in[4], (float*)d_ws,
        WIHT_N + WKC_N);
    policy_g<<<BATCH / EPBS, 512, 0, stream>>>(
        (const float*)d_in[1], (const float*)d_in[2], (const float*)d_in[3],
        (const float*)d_in[5], (const float*)d_in[6],
        (const float*)d_ws, (const float*)d_ws + WIHT_N, nullptr,
        (float*)d_out);
  } else {                                     // tier C: dynamic-LDS fallback
    const float* wT = nullptr;
    if (ws_size >= need_wt) {
      prep_ws32<<<(WIHT_N + 255) / 256, 256, 0, stream>>>(
          (const float*)d_in[0], (const float*)d_in[4], (float*)d_ws, WIHT_N);
      wT = (const float*)d_ws;
    }
    hipFuncSetAttribute((const void*)policy_l,
                        hipFuncAttributeMaxDynamicSharedMemorySize,
                        (int)sizeof(SmemD));
    policy_l<<<BATCH / EPB, 1024, sizeof(SmemD), stream>>>(
        (const float*)d_in[0], (const float*)d_in[1], (const float*)d_in[2],
        (const float*)d_in[3], (const float*)d_in[4], (const float*)d_in[5],
        (const float*)d_in[6], wT, (float*)d_out);
  }
}

// Round 10
// 829.096 us; speedup vs baseline: 1.2620x; 1.2620x over previous
//
#include <hip/hip_runtime.h>
#include <math.h>

#define NOUTK 1024
#define PHK   512
#define HID   24
#define G4    96
#define LSTEPS 32
#define BATCH 8192
#define EPB   16        // fallback kernel's elements/block
#define EPBS  8         // main kernel: 8 elements / 512-thread block

// ---------------- main path: EPBS=8, 512-thread blocks, ~19.1 KB LDS -------
// R8 configuration (proven 824us). R9's f64-prewiden variant REGRESSED
// (VALUBusy 69->42%): removing the cvt stream removed the VALU work that hid
// weight-load latency, and f64 loads doubled bytes/iter. f32 weights +
// unroll 2 restored here.
struct SmemS {
  float  whhT[HID][G4];       // w_hh transposed [k][row]                9216 B
  float  blin[NOUTK];         // b_lin f32                               4096 B
  float  bihs[G4], bhhs[G4];  //                                          768 B
  double hsh[EPBS][25];       // h state f64 (pad 25)                    1600 B
  double scrM[8][EPBS];       // max partials                             512 B
  double scrS[8][EPBS];       // sum partials                             512 B
  double candr[8][EPBS];      // crossing candidate probs                 512 B
  double tots[8][EPBS];       // per-slice prob totals                    512 B
  double r0sh[EPBS];          //                                           64 B
  float  ubuf[LSTEPS][EPBS];  // all 32 steps of u                       1024 B
  int    candj[8][EPBS];      //                                          256 B
  int    actsh[EPBS];         // previous action (-1 = zeros one-hot)      32 B
};

// ---------------- fallback (ws too small): R5's proven dynamic-LDS kernel --
struct SmemD {
  float  stg[HID][128][8];
  float  whhT[HID][G4];
  float  blin[NOUTK];
  float  bihs[G4], bhhs[G4];
  double hsh[EPB][25];
  double scrM[8][EPB];
  double scrS[8][EPB];
  double candr[8][EPB];
  double tots[8][EPB];
  double r0sh[EPB];
  float  ubuf[LSTEPS][EPB];
  int    candj[8][EPB];
  int    actsh[EPB];
};

__device__ __forceinline__ float bf2f(unsigned short v) {
  union { unsigned u; float f; } x; x.u = ((unsigned)v) << 16; return x.f;
}
__device__ __forceinline__ unsigned short f2bf(float f) {
  unsigned u = __float_as_uint(f);
  unsigned r = 0x7FFFu + ((u >> 16) & 1u);
  return (unsigned short)((u + r) >> 16);
}
__device__ __forceinline__ float bfsnap(float f) { return bf2f(f2bf(f)); }

// One-time workspace prep:
//   ws[0 .. 98303]        = wihT  [1024][96]
//   ws[98304 .. 122879]   = wlinKC[24][1024]
__global__ void __launch_bounds__(256)
prep_ws(const float* __restrict__ wihf, const float* __restrict__ wlinf,
        float* __restrict__ ws, int total) {
  const int idx = blockIdx.x * 256 + threadIdx.x;
  if (idx >= total) return;
  if (idx < NOUTK * G4) {
    const int j = idx / G4;                    // column of w_ih  0..1023
    const int r = idx - j * G4;                // row of w_ih     0..95
    ws[idx] = wihf[r * NOUTK + j];
  } else {
    const int i2  = idx - NOUTK * G4;
    const int k   = i2 >> 10;                  // 0..23
    const int col = i2 & (NOUTK - 1);          // 0..1023
    ws[idx] = wlinf[col * HID + k];
  }
}

// Session ledger (dur / VALUBusy / Occupancy / spill):
//   R8  f32 weights, unroll 2:  824us / 69% / 72% / 32MB   <- BEST, this file
//   R9  f64 weights, unroll 1: 1046us / 43% / 72% / 26MB   <- latency-exposed
// At the 32-wave HW cap with HBM ~0.6% and bank conflicts ~0.4%, the ~30%
// non-busy is the 6-barrier/step recurrent structure + residual spill (~1-2%).
__global__ void __launch_bounds__(512, 8)
policy_g(const float* __restrict__ whhf,  const float* __restrict__ bihf,
         const float* __restrict__ bhhf,  const float* __restrict__ blinf,
         const float* __restrict__ uf,    const float* __restrict__ wT,
         const float* __restrict__ wKC,   float* __restrict__ outg) {
  __shared__ SmemS smS;
  SmemS* sm = &smS;
  const int tid  = threadIdx.x;
  const int wave = tid >> 6;                 // 8 waves
  const int lane = tid & 63;
  const int s    = wave;                     // slice: 64 active cols
  const int le   = lane & 7;                 // element within block (0..7)
  const int jl   = lane >> 3;                // 8-col chunk within slice
  const int eG   = le;                       // element this thread computes for
  const int geL  = blockIdx.x * EPBS + wave; // owner's global batch element
  const int jgl0 = s * 64 + jl * 8;          // active-local col of r=0

  // ---------------- one-time staging ------------------------------------
  for (int i = tid; i < G4 * HID; i += 512) {
    const int row = i / HID, k = i % HID;    // coalesced global read
    sm->whhT[k][row] = whhf[i];
  }
  for (int i = tid; i < NOUTK; i += 512) sm->blin[i] = blinf[i];
  if (tid < G4) { sm->bihs[tid] = bihf[tid]; sm->bhhs[tid] = bhhf[tid]; }
  if (tid < EPBS * 25) ((double*)sm->hsh)[tid] = 0.0;
  if (tid < EPBS) sm->actsh[tid] = -1;
  if (tid < LSTEPS * EPBS) {                 // preload ALL u for this block
    const int t = tid >> 3, e = tid & 7;
    sm->ubuf[t][e] = uf[t * BATCH + blockIdx.x * EPBS + e];
  }

  double creg = 0.0;          // c state: waves 0-3, lanes {0-23, 32-55}
  __syncthreads();

  for (int t = 0; t < LSTEPS; ++t) {
    const int odd  = t & 1;
    const int base = odd ? PHK : 0;

    // ---------------- phase L: LSTM cell, 2 elements per wave ------------
    if (wave < 4 && (lane & 31) < HID) {
      const int eL = (wave << 1) + (lane >> 5);   // element 0..7
      const int rl = lane & 31;                   // row within gate (0..23)
      const int a  = sm->actsh[eL];
      double g0, g1, g2, g3;
#define GATE(Q, GOUT)                                                        \
      { const int row = (Q) * HID + rl;                                      \
        const double colA = (a >= 0) ? (double)wT[a * G4 + row] : 0.0;       \
        double mv = 0.0;                                                     \
        _Pragma("unroll 4")                                                  \
        for (int k = 0; k < HID; ++k)                                        \
          mv = fma(sm->hsh[eL][k], (double)sm->whhT[k][row], mv);            \
        GOUT = ((colA + (double)sm->bihs[row]) + mv) + (double)sm->bhhs[row]; \
        __builtin_amdgcn_sched_barrier(0); }
      GATE(0, g0) GATE(1, g1) GATE(2, g2) GATE(3, g3)
#undef GATE
      const double ig = 1.0 / (1.0 + exp(-g0));
      const double fg = 1.0 / (1.0 + exp(-g1));
      const double gv = tanh(g2);
      const double og = 1.0 / (1.0 + exp(-g3));
      creg = fg * creg + ig * gv;
      sm->hsh[eL][rl] = og * tanh(creg);
    }
    __syncthreads();                                  // b1

    // ---------------- phase G: logits from GLOBAL wlinKC (L1/L2-hit) -----
    // f32 weights + unroll 2: the cvt stream co-issues with and hides the
    // weight-load latency (R9 lesson: do NOT remove it).
    double z0 = 0.0, z1 = 0.0, z2 = 0.0, z3 = 0.0,
           z4 = 0.0, z5 = 0.0, z6 = 0.0, z7 = 0.0;
    const float* __restrict__ wrow = wKC + (base + jgl0);
    #pragma unroll 2
    for (int k = 0; k < HID; ++k) {
      const double hv = sm->hsh[eG][k];
      const float4 wa = *(const float4*)(wrow + k * NOUTK);
      const float4 wb = *(const float4*)(wrow + k * NOUTK + 4);
      z0 = fma(hv, (double)wa.x, z0); z1 = fma(hv, (double)wa.y, z1);
      z2 = fma(hv, (double)wa.z, z2); z3 = fma(hv, (double)wa.w, z3);
      z4 = fma(hv, (double)wb.x, z4); z5 = fma(hv, (double)wb.y, z5);
      z6 = fma(hv, (double)wb.z, z6); z7 = fma(hv, (double)wb.w, z7);
    }
    {
      const float4 ba = *(const float4*)&sm->blin[base + jgl0];
      const float4 bb = *(const float4*)&sm->blin[base + jgl0 + 4];
      z0 += (double)ba.x; z1 += (double)ba.y; z2 += (double)ba.z; z3 += (double)ba.w;
      z4 += (double)bb.x; z5 += (double)bb.y; z6 += (double)bb.z; z7 += (double)bb.w;
    }

    // ---------------- softmax max: partials -> ONE barrier -> self-serve -
    double pm = fmax(fmax(fmax(z0, z1), fmax(z2, z3)),
                     fmax(fmax(z4, z5), fmax(z6, z7)));
    pm = fmax(pm, __shfl_xor(pm, 8));
    pm = fmax(pm, __shfl_xor(pm, 16));
    pm = fmax(pm, __shfl_xor(pm, 32));
    if (jl == 0) sm->scrM[s][eG] = pm;
    __syncthreads();                                  // B2
    double Me;
    {
      const double s0 = sm->scrM[0][eG], s1 = sm->scrM[1][eG],
                   s2 = sm->scrM[2][eG], s3 = sm->scrM[3][eG],
                   s4 = sm->scrM[4][eG], s5 = sm->scrM[5][eG],
                   s6 = sm->scrM[6][eG], s7 = sm->scrM[7][eG];
      Me = fmax(fmax(fmax(s0, s1), fmax(s2, s3)),
                fmax(fmax(s4, s5), fmax(s6, s7)));
    }

    // ---------------- exp (fenced pairs) + masked-sum partials ----
    z0 = exp(z0 - Me); z1 = exp(z1 - Me);
    __builtin_amdgcn_sched_barrier(0);
    z2 = exp(z2 - Me); z3 = exp(z3 - Me);
    __builtin_amdgcn_sched_barrier(0);
    z4 = exp(z4 - Me); z5 = exp(z5 - Me);
    __builtin_amdgcn_sched_barrier(0);
    z6 = exp(z6 - Me); z7 = exp(z7 - Me);
    double ps = ((((((z0 + z1) + z2) + z3) + z4) + z5) + z6) + z7;
    ps += __shfl_xor(ps, 8);
    ps += __shfl_xor(ps, 16);
    ps += __shfl_xor(ps, 32);
    if (jl == 0) sm->scrS[s][eG] = ps;
    __syncthreads();                                  // B4
    double inv;
    {
      const double s0 = sm->scrS[0][eG], s1 = sm->scrS[1][eG],
                   s2 = sm->scrS[2][eG], s3 = sm->scrS[3][eG],
                   s4 = sm->scrS[4][eG], s5 = sm->scrS[5][eG],
                   s6 = sm->scrS[6][eG], s7 = sm->scrS[7][eG];
      inv = 1.0 / (((s0 + s1) + (s2 + s3)) + ((s4 + s5) + (s6 + s7)));
    }

    // ---------------- rr = e/Sm, blocked prefix (z's die here) ----
    const double p0 = z0 * inv,      p1 = p0 + z1 * inv,
                 p2 = p1 + z2 * inv, p3 = p2 + z3 * inv;
    const double p4 = p3 + z4 * inv, p5 = p4 + z5 * inv,
                 p6 = p5 + z6 * inv, p7 = p6 + z7 * inv;
    double exbase = 0.0, acc = 0.0;
    #pragma unroll
    for (int q2 = 0; q2 < 8; ++q2) {
      const double tq = __shfl(p7, q2 * 8 + le);
      if (q2 == jl) exbase = acc;
      acc += tq;
    }
    if (jl == 0) sm->tots[s][eG] = acc;
    if (s == 0 && lane < 8) sm->r0sh[eG] = p0;        // p0 == z0*inv exactly
    __syncthreads();                                  // b6

    // ---------------- crossing search ----
    double sb = exbase;
    for (int i = 0; i < s; ++i) sb += sm->tots[i][eG];
    const double ue = (double)sm->ubuf[t][eG];
    int jloc = 0x7FFFFFFF; double rsel = 0.0;
#define CROSS(R, PR, PRM1)                                                   \
    { const double C = sb + PR;                                              \
      if (jloc == 0x7FFFFFFF && C > ue) {                                    \
        jloc = jgl0 + (R); rsel = ((R) == 0) ? (PR) : ((PR) - (PRM1)); } }
    CROSS(0, p0, p0) CROSS(1, p1, p0) CROSS(2, p2, p1) CROSS(3, p3, p2)
    CROSS(4, p4, p3) CROSS(5, p5, p4) CROSS(6, p6, p5) CROSS(7, p7, p6)
#undef CROSS
    { int oj = __shfl_xor(jloc, 8);  double orr = __shfl_xor(rsel, 8);  if (oj < jloc) { jloc = oj; rsel = orr; } }
    { int oj = __shfl_xor(jloc, 16); double orr = __shfl_xor(rsel, 16); if (oj < jloc) { jloc = oj; rsel = orr; } }
    { int oj = __shfl_xor(jloc, 32); double orr = __shfl_xor(rsel, 32); if (oj < jloc) { jloc = oj; rsel = orr; } }
    if (jl == 0) { sm->candj[s][eG] = jloc; sm->candr[s][eG] = rsel; }
    __syncthreads();                                  // b7

    // ---------------- owner: combine slices, emit (wave w = element w) ---
    if (lane < 8) {
      int cj = sm->candj[lane][wave]; double cr = sm->candr[lane][wave];
      { int oj = __shfl_xor(cj, 1); double orr = __shfl_xor(cr, 1); if (oj < cj) { cj = oj; cr = orr; } }
      { int oj = __shfl_xor(cj, 2); double orr = __shfl_xor(cr, 2); if (oj < cj) { cj = oj; cr = orr; } }
      { int oj = __shfl_xor(cj, 4); double orr = __shfl_xor(cr, 4); if (oj < cj) { cj = oj; cr = orr; } }
      if (lane == 0) {
        int actg; double p;
        if (cj == 0x7FFFFFFF) {               // cumsum never exceeded u:
          actg = 0;                           // np.argmax(all False) == 0
          p = odd ? 0.0 : sm->r0sh[wave];     // out[0] (masked -> 0 on odd)
        } else {
          actg = base + cj; p = cr;
        }
        sm->actsh[wave] = actg;
        const int io = geL * LSTEPS + t;
        outg[io]                  = bfsnap((float)p);
        outg[BATCH * LSTEPS + io] = bfsnap((float)actg);
      }
    }
    __syncthreads();                                  // b8: fence actsh for
                                                      // phase-L of t+1
  }
}

// ---------------- fallback: R5's proven dynamic-LDS kernel (unchanged) -----
__global__ void __launch_bounds__(1024)
policy_l(const float* __restrict__ wihf,  const float* __restrict__ whhf,
         const float* __restrict__ bihf,  const float* __restrict__ bhhf,
         const float* __restrict__ wlinf, const float* __restrict__ blinf,
         const float* __restrict__ uf,    const float* __restrict__ wT,
         float* __restrict__ outg) {
  extern __shared__ char smraw[];
  SmemD* sm = (SmemD*)smraw;
  const int tid  = threadIdx.x;
  const int wave = tid >> 6;
  const int lane = tid & 63;
  const int s    = wave & 7;
  const int eg   = (wave >> 3) << 3;
  const int le   = lane & 7;
  const int jl   = lane >> 3;
  const int eG   = eg + le;
  const int geL  = blockIdx.x * EPB + wave;
  const int jgl0 = s * 64 + jl * 8;

  {
    const float4* row4 = (const float4*)(wlinf + tid * HID);
    #pragma unroll
    for (int q = 0; q < 6; ++q) {
      const float4 v = row4[q];
      sm->stg[q * 4 + 0][tid >> 3][tid & 7] = v.x;
      sm->stg[q * 4 + 1][tid >> 3][tid & 7] = v.y;
      sm->stg[q * 4 + 2][tid >> 3][tid & 7] = v.z;
      sm->stg[q * 4 + 3][tid >> 3][tid & 7] = v.w;
    }
  }
  for (int i = tid; i < G4 * HID; i += 1024) {
    const int row = i / HID, k = i % HID;
    sm->whhT[k][row] = whhf[i];
  }
  sm->blin[tid] = blinf[tid];
  if (tid < G4) { sm->bihs[tid] = bihf[tid]; sm->bhhs[tid] = bhhf[tid]; }
  if (tid < EPB * 25) ((double*)sm->hsh)[tid] = 0.0;
  if (tid < EPB) sm->actsh[tid] = -1;
  if (tid < LSTEPS * EPB) {
    const int t = tid >> 4, e = tid & 15;
    sm->ubuf[t][e] = uf[t * BATCH + blockIdx.x * EPB + e];
  }

  double creg = 0.0;
  __syncthreads();

  for (int t = 0; t < LSTEPS; ++t) {
    const int odd  = t & 1;
    const int base = odd ? PHK : 0;
    const int c    = (base >> 3) + s * 8 + jl;

    if (wave < 8 && (lane & 31) < HID) {
      const int eL = (wave << 1) + (lane >> 5);
      const int rl = lane & 31;
      const int a  = sm->actsh[eL];
      double g0, g1, g2, g3;
#define GATE(Q, GOUT)                                                        \
      { const int row = (Q) * HID + rl;                                      \
        const double colA = (a >= 0)                                         \
            ? (double)(wT ? wT[a * G4 + row] : wihf[row * NOUTK + a])        \
            : 0.0;                                                           \
        double mv = 0.0;                                                     \
        _Pragma("unroll 4")                                                  \
        for (int k = 0; k < HID; ++k)                                        \
          mv = fma(sm->hsh[eL][k], (double)sm->whhT[k][row], mv);            \
        GOUT = ((colA + (double)sm->bihs[row]) + mv) + (double)sm->bhhs[row]; \
        __builtin_amdgcn_sched_barrier(0); }
      GATE(0, g0) GATE(1, g1) GATE(2, g2) GATE(3, g3)
#undef GATE
      const double ig = 1.0 / (1.0 + exp(-g0));
      const double fg = 1.0 / (1.0 + exp(-g1));
      const double gv = tanh(g2);
      const double og = 1.0 / (1.0 + exp(-g3));
      creg = fg * creg + ig * gv;
      sm->hsh[eL][rl] = og * tanh(creg);
    }
    __syncthreads();

    double z0 = 0.0, z1 = 0.0, z2 = 0.0, z3 = 0.0,
           z4 = 0.0, z5 = 0.0, z6 = 0.0, z7 = 0.0;
    #pragma unroll 2
    for (int k = 0; k < HID; ++k) {
      const double hv = sm->hsh[eG][k];
      const float4 wa = *(const float4*)&sm->stg[k][c][0];
      const float4 wb = *(const float4*)&sm->stg[k][c][4];
      z0 = fma(hv, (double)wa.x, z0); z1 = fma(hv, (double)wa.y, z1);
      z2 = fma(hv, (double)wa.z, z2); z3 = fma(hv, (double)wa.w, z3);
      z4 = fma(hv, (double)wb.x, z4); z5 = fma(hv, (double)wb.y, z5);
      z6 = fma(hv, (double)wb.z, z6); z7 = fma(hv, (double)wb.w, z7);
    }
    {
      const float4 ba = *(const float4*)&sm->blin[base + jgl0];
      const float4 bb = *(const float4*)&sm->blin[base + jgl0 + 4];
      z0 += (double)ba.x; z1 += (double)ba.y; z2 += (double)ba.z; z3 += (double)ba.w;
      z4 += (double)bb.x; z5 += (double)bb.y; z6 += (double)bb.z; z7 += (double)bb.w;
    }

    double pm = fmax(fmax(fmax(z0, z1), fmax(z2, z3)),
                     fmax(fmax(z4, z5), fmax(z6, z7)));
    pm = fmax(pm, __shfl_xor(pm, 8));
    pm = fmax(pm, __shfl_xor(pm, 16));
    pm = fmax(pm, __shfl_xor(pm, 32));
    if (jl == 0) sm->scrM[s][eG] = pm;
    __syncthreads();
    double Me;
    {
      const double s0 = sm->scrM[0][eG], s1 = sm->scrM[1][eG],
                   s2 = sm->scrM[2][eG], s3 = sm->scrM[3][eG],
                   s4 = sm->scrM[4][eG], s5 = sm->scrM[5][eG],
                   s6 = sm->scrM[6][eG], s7 = sm->scrM[7][eG];
      Me = fmax(fmax(fmax(s0, s1), fmax(s2, s3)),
                fmax(fmax(s4, s5), fmax(s6, s7)));
    }

    z0 = exp(z0 - Me); z1 = exp(z1 - Me);
    __builtin_amdgcn_sched_barrier(0);
    z2 = exp(z2 - Me); z3 = exp(z3 - Me);
    __builtin_amdgcn_sched_barrier(0);
    z4 = exp(z4 - Me); z5 = exp(z5 - Me);
    __builtin_amdgcn_sched_barrier(0);
    z6 = exp(z6 - Me); z7 = exp(z7 - Me);
    double ps = ((((((z0 + z1) + z2) + z3) + z4) + z5) + z6) + z7;
    ps += __shfl_xor(ps, 8);
    ps += __shfl_xor(ps, 16);
    ps += __shfl_xor(ps, 32);
    if (jl == 0) sm->scrS[s][eG] = ps;
    __syncthreads();
    double inv;
    {
      const double s0 = sm->scrS[0][eG], s1 = sm->scrS[1][eG],
                   s2 = sm->scrS[2][eG], s3 = sm->scrS[3][eG],
                   s4 = sm->scrS[4][eG], s5 = sm->scrS[5][eG],
                   s6 = sm->scrS[6][eG], s7 = sm->scrS[7][eG];
      inv = 1.0 / (((s0 + s1) + (s2 + s3)) + ((s4 + s5) + (s6 + s7)));
    }

    const double p0 = z0 * inv,      p1 = p0 + z1 * inv,
                 p2 = p1 + z2 * inv, p3 = p2 + z3 * inv;
    const double p4 = p3 + z4 * inv, p5 = p4 + z5 * inv,
                 p6 = p5 + z6 * inv, p7 = p6 + z7 * inv;
    double exbase = 0.0, acc = 0.0;
    #pragma unroll
    for (int q2 = 0; q2 < 8; ++q2) {
      const double tq = __shfl(p7, q2 * 8 + le);
      if (q2 == jl) exbase = acc;
      acc += tq;
    }
    if (jl == 0) sm->tots[s][eG] = acc;
    if (s == 0 && lane < 8) sm->r0sh[eG] = p0;
    __syncthreads();

    double sb = exbase;
    for (int i = 0; i < s; ++i) sb += sm->tots[i][eG];
    const double ue = (double)sm->ubuf[t][eG];
    int jloc = 0x7FFFFFFF; double rsel = 0.0;
#define CROSS(R, PR, PRM1)                                                   \
    { const double C = sb + PR;                                              \
      if (jloc == 0x7FFFFFFF && C > ue) {                                    \
        jloc = jgl0 + (R); rsel = ((R) == 0) ? (PR) : ((PR) - (PRM1)); } }
    CROSS(0, p0, p0) CROSS(1, p1, p0) CROSS(2, p2, p1) CROSS(3, p3, p2)
    CROSS(4, p4, p3) CROSS(5, p5, p4) CROSS(6, p6, p5) CROSS(7, p7, p6)
#undef CROSS
    { int oj = __shfl_xor(jloc, 8);  double orr = __shfl_xor(rsel, 8);  if (oj < jloc) { jloc = oj; rsel = orr; } }
    { int oj = __shfl_xor(jloc, 16); double orr = __shfl_xor(rsel, 16); if (oj < jloc) { jloc = oj; rsel = orr; } }
    { int oj = __shfl_xor(jloc, 32); double orr = __shfl_xor(rsel, 32); if (oj < jloc) { jloc = oj; rsel = orr; } }
    if (jl == 0) { sm->candj[s][eG] = jloc; sm->candr[s][eG] = rsel; }
    __syncthreads();

    if (lane < 8) {
      int cj = sm->candj[lane][wave]; double cr = sm->candr[lane][wave];
      { int oj = __shfl_xor(cj, 1); double orr = __shfl_xor(cr, 1); if (oj < cj) { cj = oj; cr = orr; } }
      { int oj = __shfl_xor(cj, 2); double orr = __shfl_xor(cr, 2); if (oj < cj) { cj = oj; cr = orr; } }
      { int oj = __shfl_xor(cj, 4); double orr = __shfl_xor(cr, 4); if (oj < cj) { cj = oj; cr = orr; } }
      if (lane == 0) {
        int actg; double p;
        if (cj == 0x7FFFFFFF) {
          actg = 0;
          p = odd ? 0.0 : sm->r0sh[wave];
        } else {
          actg = base + cj; p = cr;
        }
        sm->actsh[wave] = actg;
        const int io = geL * LSTEPS + t;
        outg[io]                  = bfsnap((float)p);
        outg[BATCH * LSTEPS + io] = bfsnap((float)actg);
      }
    }
    __syncthreads();   // fence actsh for phase-L of t+1 (race fix)
  }
}

extern "C" void kernel_launch(void* const* d_in, const int* in_sizes, int n_in,
                              void* d_out, int out_size, void* d_ws, size_t ws_size,
                              hipStream_t stream) {
  (void)in_sizes; (void)n_in; (void)out_size;
  constexpr int WIHT_N = NOUTK * G4;      // 98304 floats
  constexpr int WKC_N  = HID * NOUTK;     // 24576 floats
  const size_t need_full = (size_t)(WIHT_N + WKC_N) * sizeof(float);
  const size_t need_wt   = (size_t)WIHT_N * sizeof(float);

  if (ws_size >= need_full) {
    const int total = WIHT_N + WKC_N;
    prep_ws<<<(total + 255) / 256, 256, 0, stream>>>(
        (const float*)d_in[0], (const float*)d_in[4], (float*)d_ws, total);
    policy_g<<<BATCH / EPBS, 512, 0, stream>>>(
        (const float*)d_in[1], (const float*)d_in[2], (const float*)d_in[3],
        (const float*)d_in[5], (const float*)d_in[6],
        (const float*)d_ws, (const float*)d_ws + WIHT_N, (float*)d_out);
  } else {
    const float* wT = nullptr;
    if (ws_size >= need_wt) {
      prep_ws<<<(WIHT_N + 255) / 256, 256, 0, stream>>>(
          (const float*)d_in[0], (const float*)d_in[4], (float*)d_ws, WIHT_N);
      wT = (const float*)d_ws;
    }
    hipFuncSetAttribute((const void*)policy_l,
                        hipFuncAttributeMaxDynamicSharedMemorySize,
                        (int)sizeof(SmemD));
    policy_l<<<BATCH / EPB, 1024, sizeof(SmemD), stream>>>(
        (const float*)d_in[0], (const float*)d_in[1], (const float*)d_in[2],
        (const float*)d_in[3], (const float*)d_in[4], (const float*)d_in[5],
        (const float*)d_in[6], wT, (float*)d_out);
  }
}

// Round 11
// 793.077 us; speedup vs baseline: 1.3193x; 1.0454x over previous
//
#include <hip/hip_runtime.h>
#include <math.h>

#define NOUTK 1024
#define PHK   512
#define HID   24
#define G4    96
#define LSTEPS 32
#define BATCH 8192
#define EPB   16        // fallback kernel's elements/block
#define EPBS  8         // main kernel: 8 elements / 512-thread block

// ---------------- main path: EPBS=8, 512-thread blocks, ~18.6 KB LDS -------
// R11 = R8 structure with 4 barriers/step (was 6):
//  - no softmax max-shift: |z| <= 5.1 so exp(z) in [6e-3, 1.7e2] -- f64-safe;
//    p = exp(z)/Sum differs from shifted form by ~1ulp (R3-validated
//    invariance) -> decisions unchanged. Kills B2 + max reductions.
//  - owner-combine merged into phase L of t+1 (kills b8 + owner block);
//    candidates scanned via 16 broadcast LDS reads, bit-identical min-index.
struct SmemS {
  float  whhT[HID][G4];       // w_hh transposed [k][row]                9216 B
  float  blin[NOUTK];         // b_lin f32                               4096 B
  float  bihs[G4], bhhs[G4];  //                                          768 B
  double hsh[EPBS][25];       // h state f64 (pad 25)                    1600 B
  double scrS[8][EPBS];       // sum partials                             512 B
  double candr[8][EPBS];      // crossing candidate probs                 512 B
  double tots[8][EPBS];       // per-slice prob totals                    512 B
  double r0sh[EPBS];          //                                           64 B
  float  ubuf[LSTEPS][EPBS];  // all 32 steps of u                       1024 B
  int    candj[8][EPBS];      //                                          256 B
};

// ---------------- fallback (ws too small): R5's proven dynamic-LDS kernel --
struct SmemD {
  float  stg[HID][128][8];
  float  whhT[HID][G4];
  float  blin[NOUTK];
  float  bihs[G4], bhhs[G4];
  double hsh[EPB][25];
  double scrM[8][EPB];
  double scrS[8][EPB];
  double candr[8][EPB];
  double tots[8][EPB];
  double r0sh[EPB];
  float  ubuf[LSTEPS][EPB];
  int    candj[8][EPB];
  int    actsh[EPB];
};

__device__ __forceinline__ float bf2f(unsigned short v) {
  union { unsigned u; float f; } x; x.u = ((unsigned)v) << 16; return x.f;
}
__device__ __forceinline__ unsigned short f2bf(float f) {
  unsigned u = __float_as_uint(f);
  unsigned r = 0x7FFFu + ((u >> 16) & 1u);
  return (unsigned short)((u + r) >> 16);
}
__device__ __forceinline__ float bfsnap(float f) { return bf2f(f2bf(f)); }

// One-time workspace prep:
//   ws[0 .. 98303]        = wihT  [1024][96]
//   ws[98304 .. 122879]   = wlinKC[24][1024]
__global__ void __launch_bounds__(256)
prep_ws(const float* __restrict__ wihf, const float* __restrict__ wlinf,
        float* __restrict__ ws, int total) {
  const int idx = blockIdx.x * 256 + threadIdx.x;
  if (idx >= total) return;
  if (idx < NOUTK * G4) {
    const int j = idx / G4;                    // column of w_ih  0..1023
    const int r = idx - j * G4;                // row of w_ih     0..95
    ws[idx] = wihf[r * NOUTK + j];
  } else {
    const int i2  = idx - NOUTK * G4;
    const int k   = i2 >> 10;                  // 0..23
    const int col = i2 & (NOUTK - 1);          // 0..1023
    ws[idx] = wlinf[col * HID + k];
  }
}

// Session ledger (dur / VALUBusy / Occupancy / spill):
//   R8/R10 f32 wts, 6 barriers: 824-829us / 69% / 72% / 32MB  <- proven base
//   R9     f64 wts, unroll 1:   1046us / 43% (latency-exposed; reverted)
//   R11    this file: 4 barriers/step (no max-shift, combine-in-phase-L)
__global__ void __launch_bounds__(512, 8)
policy_g(const float* __restrict__ whhf,  const float* __restrict__ bihf,
         const float* __restrict__ bhhf,  const float* __restrict__ blinf,
         const float* __restrict__ uf,    const float* __restrict__ wT,
         const float* __restrict__ wKC,   float* __restrict__ outg) {
  __shared__ SmemS smS;
  SmemS* sm = &smS;
  const int tid  = threadIdx.x;
  const int wave = tid >> 6;                 // 8 waves
  const int lane = tid & 63;
  const int s    = wave;                     // slice: 64 active cols
  const int le   = lane & 7;                 // element within block (0..7)
  const int jl   = lane >> 3;                // 8-col chunk within slice
  const int eG   = le;                       // element this thread computes for
  const int geL  = blockIdx.x * EPBS + wave; // owner's global batch element
  const int jgl0 = s * 64 + jl * 8;          // active-local col of r=0
  (void)geL;

  // ---------------- one-time staging ------------------------------------
  for (int i = tid; i < G4 * HID; i += 512) {
    const int row = i / HID, k = i % HID;    // coalesced global read
    sm->whhT[k][row] = whhf[i];
  }
  for (int i = tid; i < NOUTK; i += 512) sm->blin[i] = blinf[i];
  if (tid < G4) { sm->bihs[tid] = bihf[tid]; sm->bhhs[tid] = bhhf[tid]; }
  if (tid < EPBS * 25) ((double*)sm->hsh)[tid] = 0.0;
  if (tid < LSTEPS * EPBS) {                 // preload ALL u for this block
    const int t = tid >> 3, e = tid & 7;
    sm->ubuf[t][e] = uf[t * BATCH + blockIdx.x * EPBS + e];
  }

  double creg = 0.0;          // c state: waves 0-3, lanes {0-23, 32-55}
  __syncthreads();

  for (int t = 0; t < LSTEPS; ++t) {
    const int odd  = t & 1;
    const int base = odd ? PHK : 0;

    // ---------------- phase L: combine(t-1) + emit(t-1) + LSTM cell ------
    // 2 elements per wave, waves 0-3. The combine replaces the old owner
    // block + b8: min-index over 8 slice candidates (distinct jloc values ->
    // scan is bit-identical to the old shuffle ladder), emitted by rl==0.
    if (wave < 4 && (lane & 31) < HID) {
      const int eL = (wave << 1) + (lane >> 5);   // element 0..7
      const int rl = lane & 31;                   // row within gate (0..23)
      int a;
      if (t > 0) {
        int cj = sm->candj[0][eL]; double cr = sm->candr[0][eL];
        #pragma unroll 2
        for (int i = 1; i < 8; ++i) {
          const int    oj  = sm->candj[i][eL];
          const double orr = sm->candr[i][eL];
          if (oj < cj) { cj = oj; cr = orr; }
        }
        __builtin_amdgcn_sched_barrier(0);
        const int pe = (t - 1) & 1;
        int actg; double p;
        if (cj == 0x7FFFFFFF) {               // cumsum never exceeded u:
          actg = 0;                           // np.argmax(all False) == 0
          p = pe ? 0.0 : sm->r0sh[eL];        // out[0] (masked -> 0 on odd)
        } else {
          actg = (pe ? PHK : 0) + cj; p = cr;
        }
        if (rl == 0) {
          const int io = (blockIdx.x * EPBS + eL) * LSTEPS + (t - 1);
          outg[io]                  = bfsnap((float)p);
          outg[BATCH * LSTEPS + io] = bfsnap((float)actg);
        }
        a = actg;
      } else {
        a = -1;                               // step 0: zeros one-hot
      }
      double g0, g1, g2, g3;
#define GATE(Q, GOUT)                                                        \
      { const int row = (Q) * HID + rl;                                      \
        const double colA = (a >= 0) ? (double)wT[a * G4 + row] : 0.0;       \
        double mv = 0.0;                                                     \
        _Pragma("unroll 4")                                                  \
        for (int k = 0; k < HID; ++k)                                        \
          mv = fma(sm->hsh[eL][k], (double)sm->whhT[k][row], mv);            \
        GOUT = ((colA + (double)sm->bihs[row]) + mv) + (double)sm->bhhs[row]; \
        __builtin_amdgcn_sched_barrier(0); }
      GATE(0, g0) GATE(1, g1) GATE(2, g2) GATE(3, g3)
#undef GATE
      const double ig = 1.0 / (1.0 + exp(-g0));
      const double fg = 1.0 / (1.0 + exp(-g1));
      const double gv = tanh(g2);
      const double og = 1.0 / (1.0 + exp(-g3));
      creg = fg * creg + ig * gv;
      sm->hsh[eL][rl] = og * tanh(creg);
    }
    __syncthreads();                                  // b1

    // ---------------- phase G: logits from GLOBAL wlinKC (L1/L2-hit) -----
    // f32 weights + unroll 2: the cvt stream co-issues with and hides the
    // weight-load latency (R9 lesson: do NOT remove it).
    double z0 = 0.0, z1 = 0.0, z2 = 0.0, z3 = 0.0,
           z4 = 0.0, z5 = 0.0, z6 = 0.0, z7 = 0.0;
    const float* __restrict__ wrow = wKC + (base + jgl0);
    #pragma unroll 2
    for (int k = 0; k < HID; ++k) {
      const double hv = sm->hsh[eG][k];
      const float4 wa = *(const float4*)(wrow + k * NOUTK);
      const float4 wb = *(const float4*)(wrow + k * NOUTK + 4);
      z0 = fma(hv, (double)wa.x, z0); z1 = fma(hv, (double)wa.y, z1);
      z2 = fma(hv, (double)wa.z, z2); z3 = fma(hv, (double)wa.w, z3);
      z4 = fma(hv, (double)wb.x, z4); z5 = fma(hv, (double)wb.y, z5);
      z6 = fma(hv, (double)wb.z, z6); z7 = fma(hv, (double)wb.w, z7);
    }
    {
      const float4 ba = *(const float4*)&sm->blin[base + jgl0];
      const float4 bb = *(const float4*)&sm->blin[base + jgl0 + 4];
      z0 += (double)ba.x; z1 += (double)ba.y; z2 += (double)ba.z; z3 += (double)ba.w;
      z4 += (double)bb.x; z5 += (double)bb.y; z6 += (double)bb.z; z7 += (double)bb.w;
    }

    // ---------------- exp DIRECT (no max-shift; |z|<=5.1 -> f64-safe) ----
    // fenced pairs bound the f64-exp temp interleave (R4's spill fix).
    z0 = exp(z0); z1 = exp(z1);
    __builtin_amdgcn_sched_barrier(0);
    z2 = exp(z2); z3 = exp(z3);
    __builtin_amdgcn_sched_barrier(0);
    z4 = exp(z4); z5 = exp(z5);
    __builtin_amdgcn_sched_barrier(0);
    z6 = exp(z6); z7 = exp(z7);
    double ps = ((((((z0 + z1) + z2) + z3) + z4) + z5) + z6) + z7;
    ps += __shfl_xor(ps, 8);
    ps += __shfl_xor(ps, 16);
    ps += __shfl_xor(ps, 32);
    if (jl == 0) sm->scrS[s][eG] = ps;
    __syncthreads();                                  // B4
    double inv;
    {
      const double s0 = sm->scrS[0][eG], s1 = sm->scrS[1][eG],
                   s2 = sm->scrS[2][eG], s3 = sm->scrS[3][eG],
                   s4 = sm->scrS[4][eG], s5 = sm->scrS[5][eG],
                   s6 = sm->scrS[6][eG], s7 = sm->scrS[7][eG];
      inv = 1.0 / (((s0 + s1) + (s2 + s3)) + ((s4 + s5) + (s6 + s7)));
    }

    // ---------------- rr = e/Sm, blocked prefix (z's die here) ----
    const double p0 = z0 * inv,      p1 = p0 + z1 * inv,
                 p2 = p1 + z2 * inv, p3 = p2 + z3 * inv;
    const double p4 = p3 + z4 * inv, p5 = p4 + z5 * inv,
                 p6 = p5 + z6 * inv, p7 = p6 + z7 * inv;
    double exbase = 0.0, acc = 0.0;
    #pragma unroll
    for (int q2 = 0; q2 < 8; ++q2) {
      const double tq = __shfl(p7, q2 * 8 + le);
      if (q2 == jl) exbase = acc;
      acc += tq;
    }
    if (jl == 0) sm->tots[s][eG] = acc;
    if (s == 0 && lane < 8) sm->r0sh[eG] = p0;        // p0 == z0*inv exactly
    __syncthreads();                                  // b6

    // ---------------- crossing search -> candidates ----
    double sb = exbase;
    for (int i = 0; i < s; ++i) sb += sm->tots[i][eG];
    const double ue = (double)sm->ubuf[t][eG];
    int jloc = 0x7FFFFFFF; double rsel = 0.0;
#define CROSS(R, PR, PRM1)                                                   \
    { const double C = sb + PR;                                              \
      if (jloc == 0x7FFFFFFF && C > ue) {                                    \
        jloc = jgl0 + (R); rsel = ((R) == 0) ? (PR) : ((PR) - (PRM1)); } }
    CROSS(0, p0, p0) CROSS(1, p1, p0) CROSS(2, p2, p1) CROSS(3, p3, p2)
    CROSS(4, p4, p3) CROSS(5, p5, p4) CROSS(6, p6, p5) CROSS(7, p7, p6)
#undef CROSS
    { int oj = __shfl_xor(jloc, 8);  double orr = __shfl_xor(rsel, 8);  if (oj < jloc) { jloc = oj; rsel = orr; } }
    { int oj = __shfl_xor(jloc, 16); double orr = __shfl_xor(rsel, 16); if (oj < jloc) { jloc = oj; rsel = orr; } }
    { int oj = __shfl_xor(jloc, 32); double orr = __shfl_xor(rsel, 32); if (oj < jloc) { jloc = oj; rsel = orr; } }
    if (jl == 0) { sm->candj[s][eG] = jloc; sm->candr[s][eG] = rsel; }
    __syncthreads();                                  // b7: fences candidate
                                                      // writes for phase-L of
                                                      // t+1 (and epilogue)
  }

  // ---------------- epilogue: combine + emit step LSTEPS-1 ----------------
  if (tid < EPBS) {
    const int e = tid;
    int cj = sm->candj[0][e]; double cr = sm->candr[0][e];
    #pragma unroll 2
    for (int i = 1; i < 8; ++i) {
      const int    oj  = sm->candj[i][e];
      const double orr = sm->candr[i][e];
      if (oj < cj) { cj = oj; cr = orr; }
    }
    const int pe = (LSTEPS - 1) & 1;                  // = 1 (odd)
    int actg; double p;
    if (cj == 0x7FFFFFFF) { actg = 0; p = pe ? 0.0 : sm->r0sh[e]; }
    else                  { actg = (pe ? PHK : 0) + cj; p = cr; }
    const int io = (blockIdx.x * EPBS + e) * LSTEPS + (LSTEPS - 1);
    outg[io]                  = bfsnap((float)p);
    outg[BATCH * LSTEPS + io] = bfsnap((float)actg);
  }
}

// ---------------- fallback: R5's proven dynamic-LDS kernel (unchanged) -----
__global__ void __launch_bounds__(1024)
policy_l(const float* __restrict__ wihf,  const float* __restrict__ whhf,
         const float* __restrict__ bihf,  const float* __restrict__ bhhf,
         const float* __restrict__ wlinf, const float* __restrict__ blinf,
         const float* __restrict__ uf,    const float* __restrict__ wT,
         float* __restrict__ outg) {
  extern __shared__ char smraw[];
  SmemD* sm = (SmemD*)smraw;
  const int tid  = threadIdx.x;
  const int wave = tid >> 6;
  const int lane = tid & 63;
  const int s    = wave & 7;
  const int eg   = (wave >> 3) << 3;
  const int le   = lane & 7;
  const int jl   = lane >> 3;
  const int eG   = eg + le;
  const int geL  = blockIdx.x * EPB + wave;
  const int jgl0 = s * 64 + jl * 8;

  {
    const float4* row4 = (const float4*)(wlinf + tid * HID);
    #pragma unroll
    for (int q = 0; q < 6; ++q) {
      const float4 v = row4[q];
      sm->stg[q * 4 + 0][tid >> 3][tid & 7] = v.x;
      sm->stg[q * 4 + 1][tid >> 3][tid & 7] = v.y;
      sm->stg[q * 4 + 2][tid >> 3][tid & 7] = v.z;
      sm->stg[q * 4 + 3][tid >> 3][tid & 7] = v.w;
    }
  }
  for (int i = tid; i < G4 * HID; i += 1024) {
    const int row = i / HID, k = i % HID;
    sm->whhT[k][row] = whhf[i];
  }
  sm->blin[tid] = blinf[tid];
  if (tid < G4) { sm->bihs[tid] = bihf[tid]; sm->bhhs[tid] = bhhf[tid]; }
  if (tid < EPB * 25) ((double*)sm->hsh)[tid] = 0.0;
  if (tid < EPB) sm->actsh[tid] = -1;
  if (tid < LSTEPS * EPB) {
    const int t = tid >> 4, e = tid & 15;
    sm->ubuf[t][e] = uf[t * BATCH + blockIdx.x * EPB + e];
  }

  double creg = 0.0;
  __syncthreads();

  for (int t = 0; t < LSTEPS; ++t) {
    const int odd  = t & 1;
    const int base = odd ? PHK : 0;
    const int c    = (base >> 3) + s * 8 + jl;

    if (wave < 8 && (lane & 31) < HID) {
      const int eL = (wave << 1) + (lane >> 5);
      const int rl = lane & 31;
      const int a  = sm->actsh[eL];
      double g0, g1, g2, g3;
#define GATE(Q, GOUT)                                                        \
      { const int row = (Q) * HID + rl;                                      \
        const double colA = (a >= 0)                                         \
            ? (double)(wT ? wT[a * G4 + row] : wihf[row * NOUTK + a])        \
            : 0.0;                                                           \
        double mv = 0.0;                                                     \
        _Pragma("unroll 4")                                                  \
        for (int k = 0; k < HID; ++k)                                        \
          mv = fma(sm->hsh[eL][k], (double)sm->whhT[k][row], mv);            \
        GOUT = ((colA + (double)sm->bihs[row]) + mv) + (double)sm->bhhs[row]; \
        __builtin_amdgcn_sched_barrier(0); }
      GATE(0, g0) GATE(1, g1) GATE(2, g2) GATE(3, g3)
#undef GATE
      const double ig = 1.0 / (1.0 + exp(-g0));
      const double fg = 1.0 / (1.0 + exp(-g1));
      const double gv = tanh(g2);
      const double og = 1.0 / (1.0 + exp(-g3));
      creg = fg * creg + ig * gv;
      sm->hsh[eL][rl] = og * tanh(creg);
    }
    __syncthreads();

    double z0 = 0.0, z1 = 0.0, z2 = 0.0, z3 = 0.0,
           z4 = 0.0, z5 = 0.0, z6 = 0.0, z7 = 0.0;
    #pragma unroll 2
    for (int k = 0; k < HID; ++k) {
      const double hv = sm->hsh[eG][k];
      const float4 wa = *(const float4*)&sm->stg[k][c][0];
      const float4 wb = *(const float4*)&sm->stg[k][c][4];
      z0 = fma(hv, (double)wa.x, z0); z1 = fma(hv, (double)wa.y, z1);
      z2 = fma(hv, (double)wa.z, z2); z3 = fma(hv, (double)wa.w, z3);
      z4 = fma(hv, (double)wb.x, z4); z5 = fma(hv, (double)wb.y, z5);
      z6 = fma(hv, (double)wb.z, z6); z7 = fma(hv, (double)wb.w, z7);
    }
    {
      const float4 ba = *(const float4*)&sm->blin[base + jgl0];
      const float4 bb = *(const float4*)&sm->blin[base + jgl0 + 4];
      z0 += (double)ba.x; z1 += (double)ba.y; z2 += (double)ba.z; z3 += (double)ba.w;
      z4 += (double)bb.x; z5 += (double)bb.y; z6 += (double)bb.z; z7 += (double)bb.w;
    }

    double pm = fmax(fmax(fmax(z0, z1), fmax(z2, z3)),
                     fmax(fmax(z4, z5), fmax(z6, z7)));
    pm = fmax(pm, __shfl_xor(pm, 8));
    pm = fmax(pm, __shfl_xor(pm, 16));
    pm = fmax(pm, __shfl_xor(pm, 32));
    if (jl == 0) sm->scrM[s][eG] = pm;
    __syncthreads();
    double Me;
    {
      const double s0 = sm->scrM[0][eG], s1 = sm->scrM[1][eG],
                   s2 = sm->scrM[2][eG], s3 = sm->scrM[3][eG],
                   s4 = sm->scrM[4][eG], s5 = sm->scrM[5][eG],
                   s6 = sm->scrM[6][eG], s7 = sm->scrM[7][eG];
      Me = fmax(fmax(fmax(s0, s1), fmax(s2, s3)),
                fmax(fmax(s4, s5), fmax(s6, s7)));
    }

    z0 = exp(z0 - Me); z1 = exp(z1 - Me);
    __builtin_amdgcn_sched_barrier(0);
    z2 = exp(z2 - Me); z3 = exp(z3 - Me);
    __builtin_amdgcn_sched_barrier(0);
    z4 = exp(z4 - Me); z5 = exp(z5 - Me);
    __builtin_amdgcn_sched_barrier(0);
    z6 = exp(z6 - Me); z7 = exp(z7 - Me);
    double ps = ((((((z0 + z1) + z2) + z3) + z4) + z5) + z6) + z7;
    ps += __shfl_xor(ps, 8);
    ps += __shfl_xor(ps, 16);
    ps += __shfl_xor(ps, 32);
    if (jl == 0) sm->scrS[s][eG] = ps;
    __syncthreads();
    double inv;
    {
      const double s0 = sm->scrS[0][eG], s1 = sm->scrS[1][eG],
                   s2 = sm->scrS[2][eG], s3 = sm->scrS[3][eG],
                   s4 = sm->scrS[4][eG], s5 = sm->scrS[5][eG],
                   s6 = sm->scrS[6][eG], s7 = sm->scrS[7][eG];
      inv = 1.0 / (((s0 + s1) + (s2 + s3)) + ((s4 + s5) + (s6 + s7)));
    }

    const double p0 = z0 * inv,      p1 = p0 + z1 * inv,
                 p2 = p1 + z2 * inv, p3 = p2 + z3 * inv;
    const double p4 = p3 + z4 * inv, p5 = p4 + z5 * inv,
                 p6 = p5 + z6 * inv, p7 = p6 + z7 * inv;
    double exbase = 0.0, acc = 0.0;
    #pragma unroll
    for (int q2 = 0; q2 < 8; ++q2) {
      const double tq = __shfl(p7, q2 * 8 + le);
      if (q2 == jl) exbase = acc;
      acc += tq;
    }
    if (jl == 0) sm->tots[s][eG] = acc;
    if (s == 0 && lane < 8) sm->r0sh[eG] = p0;
    __syncthreads();

    double sb = exbase;
    for (int i = 0; i < s; ++i) sb += sm->tots[i][eG];
    const double ue = (double)sm->ubuf[t][eG];
    int jloc = 0x7FFFFFFF; double rsel = 0.0;
#define CROSS(R, PR, PRM1)                                                   \
    { const double C = sb + PR;                                              \
      if (jloc == 0x7FFFFFFF && C > ue) {                                    \
        jloc = jgl0 + (R); rsel = ((R) == 0) ? (PR) : ((PR) - (PRM1)); } }
    CROSS(0, p0, p0) CROSS(1, p1, p0) CROSS(2, p2, p1) CROSS(3, p3, p2)
    CROSS(4, p4, p3) CROSS(5, p5, p4) CROSS(6, p6, p5) CROSS(7, p7, p6)
#undef CROSS
    { int oj = __shfl_xor(jloc, 8);  double orr = __shfl_xor(rsel, 8);  if (oj < jloc) { jloc = oj; rsel = orr; } }
    { int oj = __shfl_xor(jloc, 16); double orr = __shfl_xor(rsel, 16); if (oj < jloc) { jloc = oj; rsel = orr; } }
    { int oj = __shfl_xor(jloc, 32); double orr = __shfl_xor(rsel, 32); if (oj < jloc) { jloc = oj; rsel = orr; } }
    if (jl == 0) { sm->candj[s][eG] = jloc; sm->candr[s][eG] = rsel; }
    __syncthreads();

    if (lane < 8) {
      int cj = sm->candj[lane][wave]; double cr = sm->candr[lane][wave];
      { int oj = __shfl_xor(cj, 1); double orr = __shfl_xor(cr, 1); if (oj < cj) { cj = oj; cr = orr; } }
      { int oj = __shfl_xor(cj, 2); double orr = __shfl_xor(cr, 2); if (oj < cj) { cj = oj; cr = orr; } }
      { int oj = __shfl_xor(cj, 4); double orr = __shfl_xor(cr, 4); if (oj < cj) { cj = oj; cr = orr; } }
      if (lane == 0) {
        int actg; double p;
        if (cj == 0x7FFFFFFF) {
          actg = 0;
          p = odd ? 0.0 : sm->r0sh[wave];
        } else {
          actg = base + cj; p = cr;
        }
        sm->actsh[wave] = actg;
        const int io = geL * LSTEPS + t;
        outg[io]                  = bfsnap((float)p);
        outg[BATCH * LSTEPS + io] = bfsnap((float)actg);
      }
    }
    __syncthreads();   // fence actsh for phase-L of t+1 (race fix)
  }
}

extern "C" void kernel_launch(void* const* d_in, const int* in_sizes, int n_in,
                              void* d_out, int out_size, void* d_ws, size_t ws_size,
                              hipStream_t stream) {
  (void)in_sizes; (void)n_in; (void)out_size;
  constexpr int WIHT_N = NOUTK * G4;      // 98304 floats
  constexpr int WKC_N  = HID * NOUTK;     // 24576 floats
  const size_t need_full = (size_t)(WIHT_N + WKC_N) * sizeof(float);
  const size_t need_wt   = (size_t)WIHT_N * sizeof(float);

  if (ws_size >= need_full) {
    const int total = WIHT_N + WKC_N;
    prep_ws<<<(total + 255) / 256, 256, 0, stream>>>(
        (const float*)d_in[0], (const float*)d_in[4], (float*)d_ws, total);
    policy_g<<<BATCH / EPBS, 512, 0, stream>>>(
        (const float*)d_in[1], (const float*)d_in[2], (const float*)d_in[3],
        (const float*)d_in[5], (const float*)d_in[6],
        (const float*)d_ws, (const float*)d_ws + WIHT_N, (float*)d_out);
  } else {
    const float* wT = nullptr;
    if (ws_size >= need_wt) {
      prep_ws<<<(WIHT_N + 255) / 256, 256, 0, stream>>>(
          (const float*)d_in[0], (const float*)d_in[4], (float*)d_ws, WIHT_N);
      wT = (const float*)d_ws;
    }
    hipFuncSetAttribute((const void*)policy_l,
                        hipFuncAttributeMaxDynamicSharedMemorySize,
                        (int)sizeof(SmemD));
    policy_l<<<BATCH / EPB, 1024, sizeof(SmemD), stream>>>(
        (const float*)d_in[0], (const float*)d_in[1], (const float*)d_in[2],
        (const float*)d_in[3], (const float*)d_in[4], (const float*)d_in[5],
        (const float*)d_in[6], wT, (float*)d_out);
  }
}